// Round 10
// baseline (429.051 us; speedup 1.0000x reference)
//
#include <hip/hip_runtime.h>

#define FDIM 128
#define MAXDEG 64     // max in-degree for Poisson(10) over 100k nodes is ~31; 64 = 2x headroom
#define GATHERB 4096  // 16 blocks/CU x 256 CUs (finer grain for balance)
#define NREP 32       // stats replica banks (atomic-contention spreading)

typedef unsigned short ushort_t;
typedef unsigned int uint_t;

// ---- bf16 helpers (bit-level; RTNE on pack) ----
__device__ __forceinline__ float bflo(uint_t u) { return __uint_as_float(u << 16); }
__device__ __forceinline__ float bfhi(uint_t u) { return __uint_as_float(u & 0xffff0000u); }
__device__ __forceinline__ ushort_t f2bf(float f) {
    uint_t u = __float_as_uint(f);
    return (ushort_t)((u + 0x7fffu + ((u >> 16) & 1u)) >> 16);
}
__device__ __forceinline__ uint_t pack2bf(float lo, float hi) {
    return (uint_t)f2bf(lo) | ((uint_t)f2bf(hi) << 16);
}

// =============== MEGA1: gemm1 (x @ W1 -> bf16) + fused [ELL fill + src hist] ===============
// 5:1 role interleave (round-6). Round-7 lesson: no further phase fusion — single register
// envelope forces gemm-loop spills. Round-9 analysis: atomic role is at the ~25 G fabric-op/s
// floor (3M ops ~ 120 us); gemm role hides inside it.
__global__ __launch_bounds__(256) void mega1_kernel(
    const float* __restrict__ x, const float* __restrict__ W,
    const int* __restrict__ src, const int* __restrict__ dst,
    int* __restrict__ cs, int* __restrict__ cursor, int* __restrict__ eidx,
    ushort_t* __restrict__ outb, int N, int E,
    int gemmB, int atomicB) {
    int bid = blockIdx.x;
    int t = threadIdx.x;

    int six = atomicB * 6;
    bool isAtomic;
    int idx;
    if (bid < six) {
        int grp = bid / 6, rem = bid % 6;
        if (rem == 5) { isAtomic = true; idx = grp; }
        else { isAtomic = false; idx = grp * 5 + rem; }
    } else {
        isAtomic = false;
        idx = atomicB * 5 + (bid - six);
    }

    if (isAtomic) {
        int stride = atomicB * 256;
        for (int i = idx * 256 + t; i < E; i += stride) {
            int d = dst[i];
            int s = src[i];
            int slot = atomicAdd(&cursor[d], 1);
            if (slot < MAXDEG) eidx[(size_t)d * MAXDEG + slot] = s;
            atomicAdd(&cs[s], 1);
        }
        return;
    }

    if (idx >= gemmB) return;
    __shared__ float xt[16][FDIM];
    int base = idx * 16;
    const float4* x4 = (const float4*)x;
#pragma unroll
    for (int i = 0; i < 2; i++) {
        int ii = t + i * 256;
        int row = ii >> 5, c4 = ii & 31;
        int grow = base + row;
        float4 v = make_float4(0.f, 0.f, 0.f, 0.f);
        if (grow < N) v = x4[(size_t)grow * 32 + c4];
        *(float4*)&xt[row][c4 * 4] = v;
    }
    __syncthreads();
    int rg = t >> 6, c = t & 63;
    float acc[4][2] = {};
    const float* Wc0 = W + c;
    for (int k4 = 0; k4 < 32; k4++) {
        float xv[16];
#pragma unroll
        for (int r = 0; r < 4; r++) {
            float4 tmp = *(const float4*)&xt[rg * 4 + r][k4 * 4];
            xv[r * 4 + 0] = tmp.x; xv[r * 4 + 1] = tmp.y;
            xv[r * 4 + 2] = tmp.z; xv[r * 4 + 3] = tmp.w;
        }
#pragma unroll
        for (int kk = 0; kk < 4; kk++) {
            float w0 = Wc0[(k4 * 4 + kk) * FDIM];
            float w1 = Wc0[(k4 * 4 + kk) * FDIM + 64];
#pragma unroll
            for (int r = 0; r < 4; r++) {
                acc[r][0] = fmaf(xv[r * 4 + kk], w0, acc[r][0]);
                acc[r][1] = fmaf(xv[r * 4 + kk], w1, acc[r][1]);
            }
        }
    }
#pragma unroll
    for (int r = 0; r < 4; r++) {
        int grow = base + rg * 4 + r;
        if (grow < N) {
            outb[(size_t)grow * FDIM + c] = f2bf(acc[r][0]);
            outb[(size_t)grow * FDIM + c + 64] = f2bf(acc[r][1]);
        }
    }
}

// =============== scale_rows: bufA[i,:] *= rsqrt(outdeg[i])  (bf16 in/out) ===============
// Hoists the per-EDGE outdeg scale out of gather1 to a per-NODE pass (1M -> 100k scales).
__global__ __launch_bounds__(256) void scale_rows_kernel(ushort_t* __restrict__ hb,
                                                         const int* __restrict__ cs, int N) {
    int gid = blockIdx.x * 256 + threadIdx.x;   // one uint4 (8 cols) per thread
    int row = gid >> 4;
    if (row >= N) return;
    uint4* p = (uint4*)hb + gid;
    uint4 u = *p;
    float s = rsqrtf((float)max(cs[row], 1));
    u.x = pack2bf(bflo(u.x) * s, bfhi(u.x) * s);
    u.y = pack2bf(bflo(u.y) * s, bfhi(u.y) * s);
    u.z = pack2bf(bflo(u.z) * s, bfhi(u.z) * s);
    u.w = pack2bf(bflo(u.w) * s, bfhi(u.w) * s);
    *p = u;
}

// =============== gather v3: 2 edges/load, 8 edges in flight; no per-edge scale ===============
// v[i,:] = (sum_e h[src_e,:]) * indeg^-1/2 + b  -> bf16; BN stats fused -> 32-replica scratch.
__global__ __launch_bounds__(256) void gather_kernel(const ushort_t* __restrict__ hb,
                                                     const int* __restrict__ eidx,
                                                     const int* __restrict__ cnt,
                                                     const float* __restrict__ b,
                                                     ushort_t* __restrict__ outb,
                                                     float* __restrict__ statsRep, int N) {
    __shared__ float4 redS[256];
    __shared__ float4 redQ[256];
    int t = threadIdx.x;
    int wave = t >> 6, lane = t & 63;
    int half = lane >> 5, sub = lane & 31;
    int gw = blockIdx.x * 4 + wave;
    const uint2* h2 = (const uint2*)hb;  // 32 uint2 (4 bf16) per 128-col row
    uint2* o2 = (uint2*)outb;
    float4 bb = ((const float4*)b)[sub];  // cols [sub*4, sub*4+4)
    float st0 = 0, st1 = 0, st2 = 0, st3 = 0, sq0 = 0, sq1 = 0, sq2 = 0, sq3 = 0;

    for (int node = gw; node < N; node += GATHERB * 4) {
        int deg = cnt[node];
        int e = min(deg, MAXDEG);
        const int* row = eidx + (size_t)node * MAXDEG;
        int ridx = (lane < e) ? row[lane] : 0;  // one coalesced per-lane load

        float a0 = 0, a1 = 0, a2 = 0, a3 = 0;
        float c0 = 0, c1 = 0, c2 = 0, c3 = 0;
        int j = 0;
        for (; j + 7 < e; j += 8) {  // 4 pair-loads in flight (8 edges)
            int iA = __shfl(ridx, j + half);
            int iB = __shfl(ridx, j + 2 + half);
            int iC = __shfl(ridx, j + 4 + half);
            int iD = __shfl(ridx, j + 6 + half);
            uint2 uA = h2[(size_t)iA * 32 + sub];
            uint2 uB = h2[(size_t)iB * 32 + sub];
            uint2 uC = h2[(size_t)iC * 32 + sub];
            uint2 uD = h2[(size_t)iD * 32 + sub];
            a0 += bflo(uA.x); a1 += bfhi(uA.x); a2 += bflo(uA.y); a3 += bfhi(uA.y);
            c0 += bflo(uB.x); c1 += bfhi(uB.x); c2 += bflo(uB.y); c3 += bfhi(uB.y);
            a0 += bflo(uC.x); a1 += bfhi(uC.x); a2 += bflo(uC.y); a3 += bfhi(uC.y);
            c0 += bflo(uD.x); c1 += bfhi(uD.x); c2 += bflo(uD.y); c3 += bfhi(uD.y);
        }
        for (; j + 3 < e; j += 4) {
            int iA = __shfl(ridx, j + half);
            int iB = __shfl(ridx, j + 2 + half);
            uint2 uA = h2[(size_t)iA * 32 + sub];
            uint2 uB = h2[(size_t)iB * 32 + sub];
            a0 += bflo(uA.x); a1 += bfhi(uA.x); a2 += bflo(uA.y); a3 += bfhi(uA.y);
            c0 += bflo(uB.x); c1 += bfhi(uB.x); c2 += bflo(uB.y); c3 += bfhi(uB.y);
        }
        for (; j < e; j += 2) {  // tail pair (possibly odd)
            int jj = j + half;
            bool take = jj < e;
            int i0 = __shfl(ridx, take ? jj : (e - 1));
            float w = take ? 1.f : 0.f;
            uint2 u = h2[(size_t)i0 * 32 + sub];
            a0 = fmaf(bflo(u.x), w, a0); a1 = fmaf(bfhi(u.x), w, a1);
            a2 = fmaf(bflo(u.y), w, a2); a3 = fmaf(bfhi(u.y), w, a3);
        }
        a0 += c0; a1 += c1; a2 += c2; a3 += c3;
        a0 += __shfl_xor(a0, 32);
        a1 += __shfl_xor(a1, 32);
        a2 += __shfl_xor(a2, 32);
        a3 += __shfl_xor(a3, 32);
        if (half == 0) {
            float isc = rsqrtf((float)max(deg, 1));
            uint2 o;
            o.x = pack2bf(fmaf(a0, isc, bb.x), fmaf(a1, isc, bb.y));
            o.y = pack2bf(fmaf(a2, isc, bb.z), fmaf(a3, isc, bb.w));
            o2[(size_t)node * 32 + sub] = o;
            float v0 = bflo(o.x), v1 = bfhi(o.x), v2 = bflo(o.y), v3 = bfhi(o.y);
            st0 += v0; st1 += v1; st2 += v2; st3 += v3;
            sq0 = fmaf(v0, v0, sq0); sq1 = fmaf(v1, v1, sq1);
            sq2 = fmaf(v2, v2, sq2); sq3 = fmaf(v3, v3, sq3);
        }
    }

    redS[t] = make_float4(st0, st1, st2, st3);  // half-1 lanes hold zeros
    redQ[t] = make_float4(sq0, sq1, sq2, sq3);
    __syncthreads();
    if (t < 32) {  // t == sub; cols [t*4, t*4+4)
        float4 s = make_float4(0, 0, 0, 0), q = make_float4(0, 0, 0, 0);
#pragma unroll
        for (int w = 0; w < 4; w++) {
            float4 a = redS[w * 64 + t];
            float4 z = redQ[w * 64 + t];
            s.x += a.x; s.y += a.y; s.z += a.z; s.w += a.w;
            q.x += z.x; q.y += z.y; q.z += z.z; q.w += z.w;
        }
        float* dstp = statsRep + (size_t)(blockIdx.x & (NREP - 1)) * 256;
        atomicAdd(&dstp[t * 4 + 0], s.x);
        atomicAdd(&dstp[t * 4 + 1], s.y);
        atomicAdd(&dstp[t * 4 + 2], s.z);
        atomicAdd(&dstp[t * 4 + 3], s.w);
        atomicAdd(&dstp[128 + t * 4 + 0], q.x);
        atomicAdd(&dstp[128 + t * 4 + 1], q.y);
        atomicAdd(&dstp[128 + t * 4 + 2], q.z);
        atomicAdd(&dstp[128 + t * 4 + 3], q.w);
    }
}

// =============== GEMM layer2: out = (relu(v*A+B) * outdeg^-1/2) @ W -> bf16 ===============
__global__ __launch_bounds__(256) void gemm2_kernel(const ushort_t* __restrict__ hb,
                                                    const float* __restrict__ W,
                                                    const int* __restrict__ cs,
                                                    const float* __restrict__ statsRep,
                                                    const float* __restrict__ g,
                                                    const float* __restrict__ be,
                                                    ushort_t* __restrict__ outb, int N,
                                                    float invN) {
    __shared__ float xt[16][FDIM];
    __shared__ float Ash[FDIM], Bsh[FDIM];
    int t = threadIdx.x;
    int base = blockIdx.x * 16;
    if (t < FDIM) {
        float s = 0.f, q = 0.f;
        for (int r = 0; r < NREP; r++) {
            s += statsRep[r * 256 + t];
            q += statsRep[r * 256 + 128 + t];
        }
        float mu = s * invN;
        float var = q * invN - mu * mu;
        float a = g[t] * rsqrtf(var + 1e-5f);
        Ash[t] = a;
        Bsh[t] = be[t] - mu * a;
    }
    __syncthreads();
    const uint2* h4 = (const uint2*)hb;
#pragma unroll
    for (int i = 0; i < 2; i++) {
        int idx = t + i * 256;
        int row = idx >> 5, gg = idx & 31;
        int grow = base + row;
        float4 v = make_float4(0.f, 0.f, 0.f, 0.f);
        if (grow < N) {
            uint2 u = h4[(size_t)grow * 32 + gg];
            float4 ab = *(const float4*)&Ash[gg * 4];
            float4 bb = *(const float4*)&Bsh[gg * 4];
            float s = rsqrtf((float)max(cs[grow], 1));
            v.x = fmaxf(fmaf(bflo(u.x), ab.x, bb.x), 0.f) * s;
            v.y = fmaxf(fmaf(bfhi(u.x), ab.y, bb.y), 0.f) * s;
            v.z = fmaxf(fmaf(bflo(u.y), ab.z, bb.z), 0.f) * s;
            v.w = fmaxf(fmaf(bfhi(u.y), ab.w, bb.w), 0.f) * s;
        }
        *(float4*)&xt[row][gg * 4] = v;
    }
    __syncthreads();
    int rg = t >> 6, c = t & 63;
    float acc[4][2] = {};
    const float* Wc0 = W + c;
    for (int k4 = 0; k4 < 32; k4++) {
        float xv[16];
#pragma unroll
        for (int r = 0; r < 4; r++) {
            float4 tmp = *(const float4*)&xt[rg * 4 + r][k4 * 4];
            xv[r * 4 + 0] = tmp.x; xv[r * 4 + 1] = tmp.y;
            xv[r * 4 + 2] = tmp.z; xv[r * 4 + 3] = tmp.w;
        }
#pragma unroll
        for (int kk = 0; kk < 4; kk++) {
            float w0 = Wc0[(k4 * 4 + kk) * FDIM];
            float w1 = Wc0[(k4 * 4 + kk) * FDIM + 64];
#pragma unroll
            for (int r = 0; r < 4; r++) {
                acc[r][0] = fmaf(xv[r * 4 + kk], w0, acc[r][0]);
                acc[r][1] = fmaf(xv[r * 4 + kk], w1, acc[r][1]);
            }
        }
    }
#pragma unroll
    for (int r = 0; r < 4; r++) {
        int grow = base + rg * 4 + r;
        if (grow < N) {
            outb[(size_t)grow * FDIM + c] = f2bf(acc[r][0]);
            outb[(size_t)grow * FDIM + c + 64] = f2bf(acc[r][1]);
        }
    }
}

// =============== classifier: out = relu(v*A+B) @ Wc + bc (fp32), replica-stats prologue ===============
__global__ __launch_bounds__(256) void cls_kernel(const ushort_t* __restrict__ hb,
                                                  const float* __restrict__ Wc,
                                                  const float* __restrict__ bc,
                                                  const float* __restrict__ statsRep,
                                                  const float* __restrict__ g,
                                                  const float* __restrict__ be,
                                                  float* __restrict__ out, int N, float invN) {
    __shared__ float wcl[FDIM * 16];   // 8 KB
    __shared__ float red[16][256];     // 16 KB
    __shared__ float Ash[FDIM], Bsh[FDIM];
    int t = threadIdx.x;
    int base = blockIdx.x * 64;
#pragma unroll
    for (int i = 0; i < 8; i++) wcl[t + i * 256] = Wc[t + i * 256];
    if (t < FDIM) {
        float s = 0.f, q = 0.f;
        for (int r = 0; r < NREP; r++) {
            s += statsRep[r * 256 + t];
            q += statsRep[r * 256 + 128 + t];
        }
        float mu = s * invN;
        float var = q * invN - mu * mu;
        float a = g[t] * rsqrtf(var + 1e-5f);
        Ash[t] = a;
        Bsh[t] = be[t] - mu * a;
    }
    __syncthreads();

    int node = base + (t >> 2);
    int q4 = t & 3;
    float acc[16];
#pragma unroll
    for (int c = 0; c < 16; c++) acc[c] = 0.f;

    if (node < N) {
        const uint2* hu2 = (const uint2*)((const uint_t*)hb + (size_t)node * 64 + q4 * 16);
        const float* Af = Ash + q4 * 32;
        const float* Bf = Bsh + q4 * 32;
#pragma unroll 1
        for (int kk = 0; kk < 8; kk++) {
            uint2 u = hu2[kk];
            float4 ab = *(const float4*)&Af[kk * 4];
            float4 bb = *(const float4*)&Bf[kk * 4];
            float v0 = fmaxf(fmaf(bflo(u.x), ab.x, bb.x), 0.f);
            float v1 = fmaxf(fmaf(bfhi(u.x), ab.y, bb.y), 0.f);
            float v2 = fmaxf(fmaf(bflo(u.y), ab.z, bb.z), 0.f);
            float v3 = fmaxf(fmaf(bfhi(u.y), ab.w, bb.w), 0.f);
            int k0 = q4 * 32 + kk * 4;
            const float* w0 = &wcl[k0 * 16];
#pragma unroll
            for (int c = 0; c < 16; c++) {
                float s = fmaf(v0, w0[c], fmaf(v1, w0[16 + c], fmaf(v2, w0[32 + c], v3 * w0[48 + c])));
                acc[c] += s;
            }
        }
    }
#pragma unroll
    for (int c = 0; c < 16; c++) red[c][t] = acc[c];
    __syncthreads();
#pragma unroll
    for (int i = t; i < 64 * 16; i += 256) {
        int n = i >> 4, c = i & 15;
        float4 p = *(const float4*)&red[c][n * 4];
        int grow = base + n;
        if (grow < N) out[(size_t)grow * 16 + c] = (p.x + p.y) + (p.z + p.w) + bc[c];
    }
}

extern "C" void kernel_launch(void* const* d_in, const int* in_sizes, int n_in,
                              void* d_out, int out_size, void* d_ws, size_t ws_size,
                              hipStream_t stream) {
    const float* x  = (const float*)d_in[0];
    const int* src  = (const int*)d_in[1];
    const int* dst  = (const int*)d_in[2];
    const float* W1 = (const float*)d_in[3];
    const float* b1 = (const float*)d_in[4];
    const float* g1 = (const float*)d_in[5];
    const float* be1= (const float*)d_in[6];
    const float* W2 = (const float*)d_in[7];
    const float* b2 = (const float*)d_in[8];
    const float* g2 = (const float*)d_in[9];
    const float* be2= (const float*)d_in[10];
    const float* Wc = (const float*)d_in[11];
    const float* bc = (const float*)d_in[12];
    float* out = (float*)d_out;

    int N = in_sizes[0] / FDIM;
    int E = in_sizes[1];
    size_t NB = (size_t)N * FDIM;

    // ---- workspace (cs | cursor | statsRep1 | statsRep2 contiguous for one memset) ----
    ushort_t* bufA = (ushort_t*)d_ws;            // [N,128] bf16
    ushort_t* bufB = bufA + NB;                  // [N,128] bf16
    int* cs        = (int*)(bufB + NB);          // [N]  out-degree
    int* cursor    = cs + N;                     // [N]  ELL cursor == in-degree
    float* statsR1 = (float*)(cursor + N);       // [NREP*256]
    float* statsR2 = statsR1 + NREP * 256;       // [NREP*256]
    int* eidx      = (int*)(statsR2 + NREP * 256);  // [N*MAXDEG]

    hipMemsetAsync(cs, 0, ((size_t)2 * N + 2 * NREP * 256) * sizeof(int), stream);

    int gemmB = (N + 15) / 16;        // 6250
    int atomicB = (gemmB + 4) / 5;    // 1250 -> exact 5:1 interleave
    int totalB = gemmB + atomicB;

    mega1_kernel<<<totalB, 256, 0, stream>>>(
        x, W1, src, dst, cs, cursor, eidx, bufA, N, E, gemmB, atomicB);

    float invN = 1.0f / N;

    // ---- layer 1: per-node outdeg scale, then plain gather (BN1 stats fused) ----
    scale_rows_kernel<<<(N * 16 + 255) / 256, 256, 0, stream>>>(bufA, cs, N);
    gather_kernel<<<GATHERB, 256, 0, stream>>>(bufA, eidx, cursor, b1, bufB, statsR1, N);

    // ---- layer 2 (row scale in gemm2; BN2 stats fused in gather2) ----
    gemm2_kernel<<<gemmB, 256, 0, stream>>>(bufB, W2, cs, statsR1, g1, be1, bufA, N, invN);
    gather_kernel<<<GATHERB, 256, 0, stream>>>(bufA, eidx, cursor, b2, bufB, statsR2, N);

    // ---- classifier ----
    cls_kernel<<<(N + 63) / 64, 256, 0, stream>>>(bufB, Wc, bc, statsR2, g2, be2, out, N, invN);
}

// Round 11
// 380.695 us; speedup vs baseline: 1.1270x; 1.1270x over previous
//
#include <hip/hip_runtime.h>

#define FDIM 128
#define MAXDEG 64     // max in-degree for Poisson(10) over 100k nodes is ~31; 64 = 2x headroom
#define GATHERB 2048  // 8 blocks/CU x 256 CUs (r10 lesson: 4096 doubles stats atomics, no gain)
#define NREP 32       // stats replica banks (atomic-contention spreading)

typedef unsigned short ushort_t;
typedef unsigned int uint_t;
typedef __attribute__((ext_vector_type(8))) short short8;    // 8 bf16 = 4 VGPR (MFMA A/B frag)
typedef __attribute__((ext_vector_type(16))) float float16;  // 32x32 MFMA C/D

// ---- bf16 helpers (bit-level; RTNE on pack) ----
__device__ __forceinline__ float bflo(uint_t u) { return __uint_as_float(u << 16); }
__device__ __forceinline__ float bfhi(uint_t u) { return __uint_as_float(u & 0xffff0000u); }
__device__ __forceinline__ ushort_t f2bf(float f) {
    uint_t u = __float_as_uint(f);
    return (ushort_t)((u + 0x7fffu + ((u >> 16) & 1u)) >> 16);
}
__device__ __forceinline__ uint_t pack2bf(float lo, float hi) {
    return (uint_t)f2bf(lo) | ((uint_t)f2bf(hi) << 16);
}

// =============== MEGA1: gemm1 (x @ W1 -> bf16) + fused [ELL fill + src hist] ===============
// 5:1 role interleave (round-6). Round-7 lesson: no further phase fusion (register envelope).
// Round-9: atomic role is at the ~25 G fabric-op/s floor; gemm role hides inside it.
__global__ __launch_bounds__(256) void mega1_kernel(
    const float* __restrict__ x, const float* __restrict__ W,
    const int* __restrict__ src, const int* __restrict__ dst,
    int* __restrict__ cs, int* __restrict__ cursor, int* __restrict__ eidx,
    ushort_t* __restrict__ outb, int N, int E,
    int gemmB, int atomicB) {
    int bid = blockIdx.x;
    int t = threadIdx.x;

    int six = atomicB * 6;
    bool isAtomic;
    int idx;
    if (bid < six) {
        int grp = bid / 6, rem = bid % 6;
        if (rem == 5) { isAtomic = true; idx = grp; }
        else { isAtomic = false; idx = grp * 5 + rem; }
    } else {
        isAtomic = false;
        idx = atomicB * 5 + (bid - six);
    }

    if (isAtomic) {
        int stride = atomicB * 256;
        for (int i = idx * 256 + t; i < E; i += stride) {
            int d = dst[i];
            int s = src[i];
            int slot = atomicAdd(&cursor[d], 1);
            if (slot < MAXDEG) eidx[(size_t)d * MAXDEG + slot] = s;
            atomicAdd(&cs[s], 1);
        }
        return;
    }

    if (idx >= gemmB) return;
    __shared__ float xt[16][FDIM];
    int base = idx * 16;
    const float4* x4 = (const float4*)x;
#pragma unroll
    for (int i = 0; i < 2; i++) {
        int ii = t + i * 256;
        int row = ii >> 5, c4 = ii & 31;
        int grow = base + row;
        float4 v = make_float4(0.f, 0.f, 0.f, 0.f);
        if (grow < N) v = x4[(size_t)grow * 32 + c4];
        *(float4*)&xt[row][c4 * 4] = v;
    }
    __syncthreads();
    int rg = t >> 6, c = t & 63;
    float acc[4][2] = {};
    const float* Wc0 = W + c;
    for (int k4 = 0; k4 < 32; k4++) {
        float xv[16];
#pragma unroll
        for (int r = 0; r < 4; r++) {
            float4 tmp = *(const float4*)&xt[rg * 4 + r][k4 * 4];
            xv[r * 4 + 0] = tmp.x; xv[r * 4 + 1] = tmp.y;
            xv[r * 4 + 2] = tmp.z; xv[r * 4 + 3] = tmp.w;
        }
#pragma unroll
        for (int kk = 0; kk < 4; kk++) {
            float w0 = Wc0[(k4 * 4 + kk) * FDIM];
            float w1 = Wc0[(k4 * 4 + kk) * FDIM + 64];
#pragma unroll
            for (int r = 0; r < 4; r++) {
                acc[r][0] = fmaf(xv[r * 4 + kk], w0, acc[r][0]);
                acc[r][1] = fmaf(xv[r * 4 + kk], w1, acc[r][1]);
            }
        }
    }
#pragma unroll
    for (int r = 0; r < 4; r++) {
        int grow = base + rg * 4 + r;
        if (grow < N) {
            outb[(size_t)grow * FDIM + c] = f2bf(acc[r][0]);
            outb[(size_t)grow * FDIM + c + 64] = f2bf(acc[r][1]);
        }
    }
}

// =============== gather (r9): 2 edges/load via half-waves; optional per-edge outdeg scale ===============
// v[i,:] = (sum_e h[src_e,:] * (OS? outdeg^-1/2 : 1)) * indeg^-1/2 + b -> bf16
// r10 lesson: cs[] per-edge loads are L2-resident (~free); do NOT hoist to a row pass.
template <bool OS>
__global__ __launch_bounds__(256) void gather_kernel(const ushort_t* __restrict__ hb,
                                                     const int* __restrict__ eidx,
                                                     const int* __restrict__ cnt,
                                                     const int* __restrict__ cs,
                                                     const float* __restrict__ b,
                                                     ushort_t* __restrict__ outb,
                                                     float* __restrict__ statsRep, int N) {
    __shared__ float4 redS[256];
    __shared__ float4 redQ[256];
    int t = threadIdx.x;
    int wave = t >> 6, lane = t & 63;
    int half = lane >> 5, sub = lane & 31;
    int gw = blockIdx.x * 4 + wave;
    const uint2* h2 = (const uint2*)hb;  // 32 uint2 (4 bf16) per 128-col row
    uint2* o2 = (uint2*)outb;
    float4 bb = ((const float4*)b)[sub];  // cols [sub*4, sub*4+4)
    float st0 = 0, st1 = 0, st2 = 0, st3 = 0, sq0 = 0, sq1 = 0, sq2 = 0, sq3 = 0;

    for (int node = gw; node < N; node += GATHERB * 4) {
        int deg = cnt[node];
        int e = min(deg, MAXDEG);
        const int* row = eidx + (size_t)node * MAXDEG;
        int ridx = (lane < e) ? row[lane] : 0;  // one coalesced per-lane load
        float scv = 1.f;
        if (OS) scv = (lane < e) ? rsqrtf((float)max(cs[ridx], 1)) : 0.f;

        float a0 = 0, a1 = 0, a2 = 0, a3 = 0;
        float c0 = 0, c1 = 0, c2 = 0, c3 = 0;
        int j = 0;
        for (; j + 3 < e; j += 4) {  // 2 pair-loads in flight (4 edges)
            int iA = __shfl(ridx, j + half);
            int iB = __shfl(ridx, j + 2 + half);
            float sA = OS ? __shfl(scv, j + half) : 1.f;
            float sB = OS ? __shfl(scv, j + 2 + half) : 1.f;
            uint2 uA = h2[(size_t)iA * 32 + sub];
            uint2 uB = h2[(size_t)iB * 32 + sub];
            a0 = fmaf(bflo(uA.x), sA, a0); a1 = fmaf(bfhi(uA.x), sA, a1);
            a2 = fmaf(bflo(uA.y), sA, a2); a3 = fmaf(bfhi(uA.y), sA, a3);
            c0 = fmaf(bflo(uB.x), sB, c0); c1 = fmaf(bfhi(uB.x), sB, c1);
            c2 = fmaf(bflo(uB.y), sB, c2); c3 = fmaf(bfhi(uB.y), sB, c3);
        }
        for (; j < e; j += 2) {  // tail pair (possibly odd)
            int jj = j + half;
            bool take = jj < e;
            int i0 = __shfl(ridx, take ? jj : (e - 1));
            float s0 = take ? (OS ? __shfl(scv, jj) : 1.f) : 0.f;
            uint2 u = h2[(size_t)i0 * 32 + sub];
            a0 = fmaf(bflo(u.x), s0, a0); a1 = fmaf(bfhi(u.x), s0, a1);
            a2 = fmaf(bflo(u.y), s0, a2); a3 = fmaf(bfhi(u.y), s0, a3);
        }
        a0 += c0; a1 += c1; a2 += c2; a3 += c3;
        a0 += __shfl_xor(a0, 32);
        a1 += __shfl_xor(a1, 32);
        a2 += __shfl_xor(a2, 32);
        a3 += __shfl_xor(a3, 32);
        if (half == 0) {
            float isc = rsqrtf((float)max(deg, 1));
            uint2 o;
            o.x = pack2bf(fmaf(a0, isc, bb.x), fmaf(a1, isc, bb.y));
            o.y = pack2bf(fmaf(a2, isc, bb.z), fmaf(a3, isc, bb.w));
            o2[(size_t)node * 32 + sub] = o;
            float v0 = bflo(o.x), v1 = bfhi(o.x), v2 = bflo(o.y), v3 = bfhi(o.y);
            st0 += v0; st1 += v1; st2 += v2; st3 += v3;
            sq0 = fmaf(v0, v0, sq0); sq1 = fmaf(v1, v1, sq1);
            sq2 = fmaf(v2, v2, sq2); sq3 = fmaf(v3, v3, sq3);
        }
    }

    redS[t] = make_float4(st0, st1, st2, st3);  // half-1 lanes hold zeros
    redQ[t] = make_float4(sq0, sq1, sq2, sq3);
    __syncthreads();
    if (t < 32) {  // t == sub; cols [t*4, t*4+4)
        float4 s = make_float4(0, 0, 0, 0), q = make_float4(0, 0, 0, 0);
#pragma unroll
        for (int w = 0; w < 4; w++) {
            float4 a = redS[w * 64 + t];
            float4 z = redQ[w * 64 + t];
            s.x += a.x; s.y += a.y; s.z += a.z; s.w += a.w;
            q.x += z.x; q.y += z.y; q.z += z.z; q.w += z.w;
        }
        float* dstp = statsRep + (size_t)(blockIdx.x & (NREP - 1)) * 256;
        atomicAdd(&dstp[t * 4 + 0], s.x);
        atomicAdd(&dstp[t * 4 + 1], s.y);
        atomicAdd(&dstp[t * 4 + 2], s.z);
        atomicAdd(&dstp[t * 4 + 3], s.w);
        atomicAdd(&dstp[128 + t * 4 + 0], q.x);
        atomicAdd(&dstp[128 + t * 4 + 1], q.y);
        atomicAdd(&dstp[128 + t * 4 + 2], q.z);
        atomicAdd(&dstp[128 + t * 4 + 3], q.w);
    }
}

// =============== GEMM layer2 (MFMA): out = (relu(v*A+B) * outdeg^-1/2) @ W -> bf16 ===============
// 64 nodes/block, 256 threads = 4 waves. v_mfma_f32_32x32x16_bf16:
//   A frag: A[m=lane&31][k = (lane>>5)*8 + j], j=0..7  (8 consecutive k -> ds_read_b128)
//   B frag: B[k][n=lane&31], same k pattern -> staged as W^T (wt[n][k])
//   C/D:    col=lane&31, row=(reg&3)+8*(reg>>2)+4*(lane>>5)   [measured: learn_hip m74/m101]
// LDS rows padded to 136 ushorts (272 B): 16B-aligned frags, worst 4-way bank alias (~1.58x).
__global__ __launch_bounds__(256) void gemm2_kernel(const ushort_t* __restrict__ hb,
                                                    const float* __restrict__ W,
                                                    const int* __restrict__ cs,
                                                    const float* __restrict__ statsRep,
                                                    const float* __restrict__ g,
                                                    const float* __restrict__ be,
                                                    ushort_t* __restrict__ outb, int N,
                                                    float invN) {
    __shared__ ushort_t zt[64][136];    // 17 KB  z-tile (BN+relu+scale, bf16)
    __shared__ ushort_t wt[128][136];   // 34 KB  W^T bf16: wt[n][k]
    __shared__ float Ash[FDIM], Bsh[FDIM];
    int t = threadIdx.x;
    int base = blockIdx.x * 64;

    if (t < FDIM) {
        float s = 0.f, q = 0.f;
        for (int r = 0; r < NREP; r++) {
            s += statsRep[r * 256 + t];
            q += statsRep[r * 256 + 128 + t];
        }
        float mu = s * invN;
        float var = q * invN - mu * mu;
        float a = g[t] * rsqrtf(var + 1e-5f);
        Ash[t] = a;
        Bsh[t] = be[t] - mu * a;
    }
    // stage W^T as bf16 (64 elems/thread, coalesced global reads)
    for (int i = t; i < FDIM * FDIM; i += 256) {
        int k = i >> 7, n = i & 127;
        wt[n][k] = f2bf(W[i]);
    }
    __syncthreads();

    // stage z-tile: BN + relu + outdeg^-1/2, packed bf16 (uint writes, conflict-free)
    const uint_t* h1 = (const uint_t*)hb;  // 2 bf16 per uint, 64 per row
    for (int i = t; i < 64 * 64; i += 256) {
        int row = i >> 6, cp = i & 63;
        int grow = base + row;
        uint_t o = 0;
        if (grow < N) {
            uint_t u = h1[(size_t)grow * 64 + cp];
            float s = rsqrtf((float)max(cs[grow], 1));
            float v0 = fmaxf(fmaf(bflo(u), Ash[cp * 2], Bsh[cp * 2]), 0.f) * s;
            float v1 = fmaxf(fmaf(bfhi(u), Ash[cp * 2 + 1], Bsh[cp * 2 + 1]), 0.f) * s;
            o = pack2bf(v0, v1);
        }
        *(uint_t*)&zt[row][cp * 2] = o;
    }
    __syncthreads();

    int wv = t >> 6, lane = t & 63;
    int rt = wv >> 1;        // row-tile 0/1 -> rows rt*32..+32
    int m = lane & 31;
    int kg = lane >> 5;      // k-group 0/1

    short8 af[8];
#pragma unroll
    for (int kk = 0; kk < 8; kk++)
        af[kk] = *(const short8*)&zt[rt * 32 + m][kk * 16 + kg * 8];

#pragma unroll
    for (int cc = 0; cc < 2; cc++) {
        int ct = (wv & 1) * 2 + cc;  // col-tile 0..3 -> cols ct*32..+32
        float16 acc = {0, 0, 0, 0, 0, 0, 0, 0, 0, 0, 0, 0, 0, 0, 0, 0};
#pragma unroll
        for (int kk = 0; kk < 8; kk++) {
            short8 bf = *(const short8*)&wt[ct * 32 + m][kk * 16 + kg * 8];
            acc = __builtin_amdgcn_mfma_f32_32x32x16_bf16(af[kk], bf, acc, 0, 0, 0);
        }
        int col = ct * 32 + m;
#pragma unroll
        for (int r = 0; r < 16; r++) {
            int row = base + rt * 32 + (r & 3) + 8 * (r >> 2) + 4 * kg;
            if (row < N) outb[(size_t)row * FDIM + col] = f2bf(acc[r]);
        }
    }
}

// =============== classifier: out = relu(v*A+B) @ Wc + bc (fp32), replica-stats prologue ===============
__global__ __launch_bounds__(256) void cls_kernel(const ushort_t* __restrict__ hb,
                                                  const float* __restrict__ Wc,
                                                  const float* __restrict__ bc,
                                                  const float* __restrict__ statsRep,
                                                  const float* __restrict__ g,
                                                  const float* __restrict__ be,
                                                  float* __restrict__ out, int N, float invN) {
    __shared__ float wcl[FDIM * 16];   // 8 KB
    __shared__ float red[16][256];     // 16 KB
    __shared__ float Ash[FDIM], Bsh[FDIM];
    int t = threadIdx.x;
    int base = blockIdx.x * 64;
#pragma unroll
    for (int i = 0; i < 8; i++) wcl[t + i * 256] = Wc[t + i * 256];
    if (t < FDIM) {
        float s = 0.f, q = 0.f;
        for (int r = 0; r < NREP; r++) {
            s += statsRep[r * 256 + t];
            q += statsRep[r * 256 + 128 + t];
        }
        float mu = s * invN;
        float var = q * invN - mu * mu;
        float a = g[t] * rsqrtf(var + 1e-5f);
        Ash[t] = a;
        Bsh[t] = be[t] - mu * a;
    }
    __syncthreads();

    int node = base + (t >> 2);
    int q4 = t & 3;
    float acc[16];
#pragma unroll
    for (int c = 0; c < 16; c++) acc[c] = 0.f;

    if (node < N) {
        const uint2* hu2 = (const uint2*)((const uint_t*)hb + (size_t)node * 64 + q4 * 16);
        const float* Af = Ash + q4 * 32;
        const float* Bf = Bsh + q4 * 32;
#pragma unroll 1
        for (int kk = 0; kk < 8; kk++) {
            uint2 u = hu2[kk];
            float4 ab = *(const float4*)&Af[kk * 4];
            float4 bb = *(const float4*)&Bf[kk * 4];
            float v0 = fmaxf(fmaf(bflo(u.x), ab.x, bb.x), 0.f);
            float v1 = fmaxf(fmaf(bfhi(u.x), ab.y, bb.y), 0.f);
            float v2 = fmaxf(fmaf(bflo(u.y), ab.z, bb.z), 0.f);
            float v3 = fmaxf(fmaf(bfhi(u.y), ab.w, bb.w), 0.f);
            int k0 = q4 * 32 + kk * 4;
            const float* w0 = &wcl[k0 * 16];
#pragma unroll
            for (int c = 0; c < 16; c++) {
                float s = fmaf(v0, w0[c], fmaf(v1, w0[16 + c], fmaf(v2, w0[32 + c], v3 * w0[48 + c])));
                acc[c] += s;
            }
        }
    }
#pragma unroll
    for (int c = 0; c < 16; c++) red[c][t] = acc[c];
    __syncthreads();
#pragma unroll
    for (int i = t; i < 64 * 16; i += 256) {
        int n = i >> 4, c = i & 15;
        float4 p = *(const float4*)&red[c][n * 4];
        int grow = base + n;
        if (grow < N) out[(size_t)grow * 16 + c] = (p.x + p.y) + (p.z + p.w) + bc[c];
    }
}

extern "C" void kernel_launch(void* const* d_in, const int* in_sizes, int n_in,
                              void* d_out, int out_size, void* d_ws, size_t ws_size,
                              hipStream_t stream) {
    const float* x  = (const float*)d_in[0];
    const int* src  = (const int*)d_in[1];
    const int* dst  = (const int*)d_in[2];
    const float* W1 = (const float*)d_in[3];
    const float* b1 = (const float*)d_in[4];
    const float* g1 = (const float*)d_in[5];
    const float* be1= (const float*)d_in[6];
    const float* W2 = (const float*)d_in[7];
    const float* b2 = (const float*)d_in[8];
    const float* g2 = (const float*)d_in[9];
    const float* be2= (const float*)d_in[10];
    const float* Wc = (const float*)d_in[11];
    const float* bc = (const float*)d_in[12];
    float* out = (float*)d_out;

    int N = in_sizes[0] / FDIM;
    int E = in_sizes[1];
    size_t NB = (size_t)N * FDIM;

    // ---- workspace (cs | cursor | statsRep1 | statsRep2 contiguous for one memset) ----
    ushort_t* bufA = (ushort_t*)d_ws;            // [N,128] bf16
    ushort_t* bufB = bufA + NB;                  // [N,128] bf16
    int* cs        = (int*)(bufB + NB);          // [N]  out-degree
    int* cursor    = cs + N;                     // [N]  ELL cursor == in-degree
    float* statsR1 = (float*)(cursor + N);       // [NREP*256]
    float* statsR2 = statsR1 + NREP * 256;       // [NREP*256]
    int* eidx      = (int*)(statsR2 + NREP * 256);  // [N*MAXDEG]

    hipMemsetAsync(cs, 0, ((size_t)2 * N + 2 * NREP * 256) * sizeof(int), stream);

    int gemmB = (N + 15) / 16;        // 6250
    int atomicB = (gemmB + 4) / 5;    // 1250 -> exact 5:1 interleave
    int totalB = gemmB + atomicB;

    mega1_kernel<<<totalB, 256, 0, stream>>>(
        x, W1, src, dst, cs, cursor, eidx, bufA, N, E, gemmB, atomicB);

    float invN = 1.0f / N;

    // ---- layer 1 (per-edge outdeg scale; BN1 stats fused -> replicas) ----
    gather_kernel<true><<<GATHERB, 256, 0, stream>>>(bufA, eidx, cursor, cs, b1, bufB, statsR1, N);

    // ---- layer 2 (MFMA gemm2 with fused BN1+relu+scale; BN2 stats fused in gather2) ----
    gemm2_kernel<<<(N + 63) / 64, 256, 0, stream>>>(bufB, W2, cs, statsR1, g1, be1, bufA, N, invN);
    gather_kernel<false><<<GATHERB, 256, 0, stream>>>(bufA, eidx, cursor, nullptr, b2, bufB, statsR2, N);

    // ---- classifier ----
    cls_kernel<<<(N + 63) / 64, 256, 0, stream>>>(bufB, Wc, bc, statsR2, g2, be2, out, N, invN);
}